// Round 8
// baseline (165.298 us; speedup 1.0000x reference)
//
#include <hip/hip_runtime.h>

#define BATCH 32768
#define DIM   256
#define NEXP  8
#define MT    16          // rows per tile (16x16x32 MFMA path)
#define STRIDE 264        // halfwords; rows 16B-aligned; frag reads 2-way-conflict max

typedef __bf16 bf16x8 __attribute__((ext_vector_type(8)));
typedef __bf16 bf16x4 __attribute__((ext_vector_type(4)));
typedef float  f32x4  __attribute__((ext_vector_type(4)));

static __device__ __forceinline__ float sigmoid_f(float x) {
    return __builtin_amdgcn_rcpf(1.f + __expf(-x));
}
static __device__ __forceinline__ float tanh_f(float x) {
    return 1.f - 2.f * __builtin_amdgcn_rcpf(__expf(2.f * x) + 1.f);
}

// ---- fused prep.
// Blocks 0..255: pack W1/W2 fp32->bf16 into 16x16x32 MFMA-B-fragment order.
// Coalesced reads (src = tid*8 floats). Layout (bf16x8 units):
//   dst = e*8192 + nt*512 + kc*64 + (kq*16 + n16),
//   element j = W[e][nt*16 + n16][kc*32 + kq*8 + j]
// so a wave's B-frag load (lane = kq*16+n16) is one contiguous 1KB line.
// Blocks 256..383: scatter sample indices into per-expert regions.
__global__ void prep_kernel(const float* __restrict__ W1, const float* __restrict__ W2,
                            const float* __restrict__ t,
                            bf16x8* __restrict__ W1p, bf16x8* __restrict__ W2p,
                            int* __restrict__ cursor, int* __restrict__ idxb) {
    const int b = blockIdx.x;
    if (b < 256) {
        const int tid = b * 256 + threadIdx.x;   // = e*8192 + col*32 + k8
        const int k8  = tid & 31;
        const int col = (tid >> 5) & 255;
        const int e   = tid >> 13;
        const int kc  = k8 >> 2;
        const int kq  = k8 & 3;
        const int n16 = col & 15;
        const int nt  = col >> 4;
        const long src = (long)tid * 8;          // consecutive floats -> coalesced
        const float4 a0 = *(const float4*)(W1 + src);
        const float4 a1 = *(const float4*)(W1 + src + 4);
        const float4 c0 = *(const float4*)(W2 + src);
        const float4 c1 = *(const float4*)(W2 + src + 4);
        bf16x8 w1, w2;
        w1[0] = (__bf16)a0.x; w1[1] = (__bf16)a0.y; w1[2] = (__bf16)a0.z; w1[3] = (__bf16)a0.w;
        w1[4] = (__bf16)a1.x; w1[5] = (__bf16)a1.y; w1[6] = (__bf16)a1.z; w1[7] = (__bf16)a1.w;
        w2[0] = (__bf16)c0.x; w2[1] = (__bf16)c0.y; w2[2] = (__bf16)c0.z; w2[3] = (__bf16)c0.w;
        w2[4] = (__bf16)c1.x; w2[5] = (__bf16)c1.y; w2[6] = (__bf16)c1.z; w2[7] = (__bf16)c1.w;
        const int dst = (e << 13) | (nt << 9) | (kc << 6) | (kq << 4) | n16;
        W1p[dst] = w1;
        W2p[dst] = w2;
    } else {
        __shared__ int h[NEXP], base[NEXP];
        if (threadIdx.x < NEXP) h[threadIdx.x] = 0;
        __syncthreads();
        const int i = (b - 256) * 256 + threadIdx.x;
        const int e = min((int)(t[i] * 8.0f), NEXP - 1);
        const int lr = atomicAdd(&h[e], 1);
        __syncthreads();
        if (threadIdx.x < NEXP)
            base[threadIdx.x] = atomicAdd(&cursor[threadIdx.x], h[threadIdx.x]);
        __syncthreads();
        idxb[e * BATCH + base[e] + lr] = i;
    }
}

// ---- grouped fused 2-layer MLP, 16-row tiles, 16x16x32 MFMA.
// 2056 tiles -> 8 blocks/CU x 4 waves = 32 waves/CU (2x R7). Small acc
// (16 AGPR) keeps VGPR<=64 for full occupancy. 2 barriers/tile (separate
// ht buffer; rows[] double-buffered).
__global__ void __launch_bounds__(256, 8)
mlp_kernel(const float* __restrict__ y,
           const float* __restrict__ scales,
           const float* __restrict__ shifta,
           const float* __restrict__ shiftb,
           const float* __restrict__ b1,
           const float* __restrict__ b2,
           const bf16x8* __restrict__ W1p,
           const bf16x8* __restrict__ W2p,
           const int* __restrict__ cnt,
           const int* __restrict__ idxb,
           float* __restrict__ out) {
    __shared__ __bf16 ab[MT * STRIDE];   // y tile (bf16)     8.4 KB
    __shared__ __bf16 ht[MT * STRIDE];   // tanh(h) tile      8.4 KB
    __shared__ int rows[2][MT];

    const int tx   = threadIdx.x;
    const int wave = tx >> 6;     // 0..3
    const int lane = tx & 63;
    const int n16  = lane & 15;   // MFMA m/n lane index
    const int quad = lane >> 4;   // 0..3
    const int ncol = wave * 64;   // wave's 64-col slice (4 nt of 16)

    int c[NEXP], tp[NEXP + 1];
    tp[0] = 0;
#pragma unroll
    for (int e = 0; e < NEXP; ++e) {
        c[e] = cnt[e];
        tp[e + 1] = tp[e] + ((c[e] + MT - 1) >> 4);
    }
    const int total = tp[NEXP];

    const float sa = sigmoid_f(shifta[0]);
    const float sb = sigmoid_f(shiftb[0]);
    const float av = -sa;
    const float bvv = sb;
    const float k1 = 0.5f * (bvv - av);
    const float k2 = 0.5f * (av + bvv);
    const bool needy = (k2 != 0.0f);    // with given inputs k2==0 exactly

    int cb = 0;
    for (int tile = blockIdx.x; tile < total; tile += gridDim.x, cb ^= 1) {
        int e = 0;
#pragma unroll
        for (int j = 0; j < NEXP; ++j) if (tile >= tp[j + 1]) e = j + 1;
        const int rbase = (tile - tp[e]) * MT;
        const int nrows = min(MT, c[e] - rbase);
        const int* idx_e = idxb + e * BATCH;

        // stage gathered y rows -> bf16 LDS tile; one row per wave per pass
        // (safe to write ab: all waves passed barrier (b) of prev tile, whose
        //  GEMM1 ab-reads precede it; rows[] double-buffered for epilogue)
#pragma unroll
        for (int pass = 0; pass < 4; ++pass) {
            const int r  = pass * 4 + wave;
            const int rr = min(r, nrows - 1);
            const int g  = idx_e[rbase + rr];
            if (lane == 0) rows[cb][r] = (r < nrows) ? g : -1;
            const float4 v = *(const float4*)(y + (long)g * DIM + lane * 4);
            bf16x4 w;
            w[0] = (__bf16)v.x; w[1] = (__bf16)v.y; w[2] = (__bf16)v.z; w[3] = (__bf16)v.w;
            *(bf16x4*)(ab + r * STRIDE + lane * 4) = w;
        }
        __syncthreads();   // (a) ab/rows staging visible

        // A-frag: A[m=n16][k = quad*8 + j], k-base kc*32
        const __bf16* apt = ab + n16 * STRIDE + quad * 8;

        // ---- GEMM1: h = y @ W1[e]^T  (A from LDS, B packed-coalesced from L2)
        const bf16x8* w1p = W1p + (e << 13) + ((ncol >> 4) << 9) + (quad << 4) + n16;
        f32x4 acc[4] = {};
#pragma unroll
        for (int kc = 0; kc < 8; ++kc) {
            bf16x8 a = *(const bf16x8*)(apt + kc * 32);
#pragma unroll
            for (int ni = 0; ni < 4; ++ni) {
                bf16x8 bb = w1p[(ni << 9) + (kc << 6)];
                acc[ni] = __builtin_amdgcn_mfma_f32_16x16x32_bf16(a, bb, acc[ni], 0, 0, 0);
            }
        }

        // ---- tanh(h + b1) -> ht (separate buffer: no barrier needed before)
        // C/D: col = n16, row = quad*4 + reg
#pragma unroll
        for (int ni = 0; ni < 4; ++ni) {
            const int n = ncol + ni * 16 + n16;
            const float b1v = b1[(e << 8) | n];
#pragma unroll
            for (int r = 0; r < 4; ++r) {
                const int row = quad * 4 + r;
                ht[row * STRIDE + n] = (__bf16)tanh_f(acc[ni][r] + b1v);
            }
        }
        __syncthreads();   // (b) ht visible; all GEMM1 ab-reads done

        // ---- GEMM2: f = h @ W2[e]^T  (A from ht)
        const __bf16* apt2 = ht + n16 * STRIDE + quad * 8;
        const bf16x8* w2p = W2p + (e << 13) + ((ncol >> 4) << 9) + (quad << 4) + n16;
        f32x4 acc2[4] = {};
#pragma unroll
        for (int kc = 0; kc < 8; ++kc) {
            bf16x8 a = *(const bf16x8*)(apt2 + kc * 32);
#pragma unroll
            for (int ni = 0; ni < 4; ++ni) {
                bf16x8 bb = w2p[(ni << 9) + (kc << 6)];
                acc2[ni] = __builtin_amdgcn_mfma_f32_16x16x32_bf16(a, bb, acc2[ni], 0, 0, 0);
            }
        }

        // ---- epilogue: out = k1*sig(scales)*(f+b2) + k2*y
#pragma unroll
        for (int ni = 0; ni < 4; ++ni) {
            const int n = ncol + ni * 16 + n16;
            const float c1  = k1 * sigmoid_f(scales[n]);
            const float b2v = b2[(e << 8) | n];
#pragma unroll
            for (int r = 0; r < 4; ++r) {
                const int row = quad * 4 + r;
                const int g = rows[cb][row];
                if (g >= 0) {
                    float res = c1 * (acc2[ni][r] + b2v);
                    if (needy) res += k2 * y[(long)g * DIM + n];
                    out[(long)g * DIM + n] = res;
                }
            }
        }
        // next iteration's staging is gated by (b) + rows double-buffer
    }
}

extern "C" void kernel_launch(void* const* d_in, const int* in_sizes, int n_in,
                              void* d_out, int out_size, void* d_ws, size_t ws_size,
                              hipStream_t stream) {
    const float* t      = (const float*)d_in[0];
    const float* y      = (const float*)d_in[1];
    const float* W1     = (const float*)d_in[2];
    const float* b1     = (const float*)d_in[3];
    const float* W2     = (const float*)d_in[4];
    const float* b2     = (const float*)d_in[5];
    const float* scales = (const float*)d_in[6];
    const float* shifta = (const float*)d_in[7];
    const float* shiftb = (const float*)d_in[8];
    float* out = (float*)d_out;

    char* ws = (char*)d_ws;
    int* cursor = (int*)ws;                               // [8]
    int* idxb   = (int*)(ws + 256);                       // [8][32768]
    bf16x8* W1p = (bf16x8*)(ws + 256 + NEXP * BATCH * 4); // packed 1MB
    bf16x8* W2p = W1p + 65536;

    hipMemsetAsync(cursor, 0, 32, stream);
    prep_kernel<<<384, 256, 0, stream>>>(W1, W2, t, W1p, W2p, cursor, idxb);
    // max tiles = 8 + 32768/16 = 2056
    mlp_kernel<<<2056, 256, 0, stream>>>(y, scales, shifta, shiftb, b1, b2,
                                         W1p, W2p, cursor, idxb, out);
}

// Round 9
// 131.968 us; speedup vs baseline: 1.2526x; 1.2526x over previous
//
#include <hip/hip_runtime.h>

#define BATCH 32768
#define DIM   256
#define NEXP  8
#define MT    32          // rows per tile
#define STRIDE 264        // DIM + 8 bf16 pad (0 conflicts measured w/ nl/kh pattern)

typedef __bf16 bf16x8 __attribute__((ext_vector_type(8)));
typedef __bf16 bf16x4 __attribute__((ext_vector_type(4)));
typedef float  f32x16 __attribute__((ext_vector_type(16)));

static __device__ __forceinline__ float sigmoid_f(float x) {
    return __builtin_amdgcn_rcpf(1.f + __expf(-x));
}
static __device__ __forceinline__ float tanh_f(float x) {
    return 1.f - 2.f * __builtin_amdgcn_rcpf(__expf(2.f * x) + 1.f);
}

// ---- fused prep (R6/R7-proven 32x32 B-frag packing).
// Blocks 0..255: pack W1/W2 fp32->bf16, layout (bf16x8 units):
//   dst = [e][nt][ks][kh*32+nl],  element j = W[e][nt*32+nl][ks*16+kh*8+j]
// -> a wave's B-frag load (lane=(kh<<5)|nl) is one contiguous 1KB line.
// Blocks 256..383: scatter sample indices into per-expert regions.
__global__ void prep_kernel(const float* __restrict__ W1, const float* __restrict__ W2,
                            const float* __restrict__ t,
                            bf16x8* __restrict__ W1p, bf16x8* __restrict__ W2p,
                            int* __restrict__ cursor, int* __restrict__ idxb) {
    const int b = blockIdx.x;
    if (b < 256) {
        const int tid = b * 256 + threadIdx.x;   // = e*8192 + col*32 + ks*2 + kh
        const int kh  = tid & 1;
        const int ks  = (tid >> 1) & 15;
        const int col = (tid >> 5) & 255;
        const int e   = tid >> 13;
        const long src = (long)tid * 8;          // consecutive floats -> coalesced
        const float4 a0 = *(const float4*)(W1 + src);
        const float4 a1 = *(const float4*)(W1 + src + 4);
        const float4 c0 = *(const float4*)(W2 + src);
        const float4 c1 = *(const float4*)(W2 + src + 4);
        bf16x8 w1, w2;
        w1[0] = (__bf16)a0.x; w1[1] = (__bf16)a0.y; w1[2] = (__bf16)a0.z; w1[3] = (__bf16)a0.w;
        w1[4] = (__bf16)a1.x; w1[5] = (__bf16)a1.y; w1[6] = (__bf16)a1.z; w1[7] = (__bf16)a1.w;
        w2[0] = (__bf16)c0.x; w2[1] = (__bf16)c0.y; w2[2] = (__bf16)c0.z; w2[3] = (__bf16)c0.w;
        w2[4] = (__bf16)c1.x; w2[5] = (__bf16)c1.y; w2[6] = (__bf16)c1.z; w2[7] = (__bf16)c1.w;
        const int dst = (e << 13) | ((col >> 5) << 10) | (ks << 6) | (kh << 5) | (col & 31);
        W1p[dst] = w1;
        W2p[dst] = w2;
    } else {
        __shared__ int h[NEXP], base[NEXP];
        if (threadIdx.x < NEXP) h[threadIdx.x] = 0;
        __syncthreads();
        const int i = (b - 256) * 256 + threadIdx.x;
        const int e = min((int)(t[i] * 8.0f), NEXP - 1);
        const int lr = atomicAdd(&h[e], 1);
        __syncthreads();
        if (threadIdx.x < NEXP)
            base[threadIdx.x] = atomicAdd(&cursor[threadIdx.x], h[threadIdx.x]);
        __syncthreads();
        idxb[e * BATCH + base[e] + lr] = i;
    }
}

// ---- grouped fused 2-layer MLP. MT=32, 512-thread blocks (8 waves), wave =
// 32 rows x 32 cols, ONE 32x32x16 acc tile (16 AGPR) -> <=64 unified regs/wave
// -> 8 waves/SIMD. Grid 1032 = 4 blocks/CU = 32 waves/CU (2x R7). All
// R4-R7-proven patterns kept: 128B-granular scattered stores, nl/kh LDS
// addressing (0 conflicts), packed-B 1KB line loads, 4-barrier single buffer.
__global__ void __launch_bounds__(512, 8)
mlp_kernel(const float* __restrict__ y,
           const float* __restrict__ scales,
           const float* __restrict__ shifta,
           const float* __restrict__ shiftb,
           const float* __restrict__ b1,
           const float* __restrict__ b2,
           const bf16x8* __restrict__ W1p,
           const bf16x8* __restrict__ W2p,
           const int* __restrict__ cnt,
           const int* __restrict__ idxb,
           float* __restrict__ out) {
    __shared__ __bf16 ab[MT * STRIDE];   // 16.9 KB: y tile (bf16), then tanh(h)
    __shared__ int rows[MT];

    const int tx   = threadIdx.x;
    const int wave = tx >> 6;     // 0..7 — also the nt (32-col) slice
    const int lane = tx & 63;
    const int nl   = lane & 31;
    const int kh   = lane >> 5;
    const int ncol = wave * 32;

    int c[NEXP], tp[NEXP + 1];
    tp[0] = 0;
#pragma unroll
    for (int e = 0; e < NEXP; ++e) {
        c[e] = cnt[e];
        tp[e + 1] = tp[e] + ((c[e] + MT - 1) >> 5);
    }
    const int total = tp[NEXP];

    const float sa = sigmoid_f(shifta[0]);
    const float sb = sigmoid_f(shiftb[0]);
    const float av = -sa;
    const float bvv = sb;
    const float k1 = 0.5f * (bvv - av);
    const float k2 = 0.5f * (av + bvv);
    const bool needy = (k2 != 0.0f);    // with given inputs k2==0 exactly

    for (int tile = blockIdx.x; tile < total; tile += gridDim.x) {
        int e = 0;
#pragma unroll
        for (int j = 0; j < NEXP; ++j) if (tile >= tp[j + 1]) e = j + 1;
        const int rbase = (tile - tp[e]) * MT;
        const int nrows = min(MT, c[e] - rbase);
        const int* idx_e = idxb + e * BATCH;

        __syncthreads();   // previous iteration's readers of ab/rows done
        // stage gathered y rows -> bf16 LDS tile; one row per wave per pass
#pragma unroll
        for (int pass = 0; pass < 4; ++pass) {
            const int r  = pass * 8 + wave;
            const int rr = min(r, nrows - 1);
            const int g  = idx_e[rbase + rr];
            if (lane == 0) rows[r] = (r < nrows) ? g : -1;
            const float4 v = *(const float4*)(y + (long)g * DIM + lane * 4);
            bf16x4 w;
            w[0] = (__bf16)v.x; w[1] = (__bf16)v.y; w[2] = (__bf16)v.z; w[3] = (__bf16)v.w;
            *(bf16x4*)(ab + r * STRIDE + lane * 4) = w;
        }
        __syncthreads();

        const __bf16* apt = ab + nl * STRIDE + kh * 8;

        // ---- GEMM1: h = y @ W1[e]^T  (A from LDS, B packed 1KB-line loads)
        const bf16x8* w1p = W1p + (e << 13) + (wave << 10) + lane;
        f32x16 acc = {};
#pragma unroll
        for (int ks = 0; ks < 16; ++ks) {
            bf16x8 a = *(const bf16x8*)(apt + ks * 16);
            acc = __builtin_amdgcn_mfma_f32_32x32x16_bf16(a, w1p[ks << 6], acc, 0, 0, 0);
        }
        __syncthreads();   // all GEMM1 reads of ab complete

        // ---- tanh(h + b1) -> ab (C/D: col=nl, row=(r&3)+8*(r>>2)+4*kh)
        {
            const int n = ncol + nl;
            const float b1v = b1[(e << 8) | n];
#pragma unroll
            for (int r = 0; r < 16; ++r) {
                const int row = (r & 3) + ((r >> 2) << 3) + (kh << 2);
                ab[row * STRIDE + n] = (__bf16)tanh_f(acc[r] + b1v);
            }
        }
        __syncthreads();

        // ---- GEMM2: f = h @ W2[e]^T
        const bf16x8* w2p = W2p + (e << 13) + (wave << 10) + lane;
        f32x16 acc2 = {};
#pragma unroll
        for (int ks = 0; ks < 16; ++ks) {
            bf16x8 a = *(const bf16x8*)(apt + ks * 16);
            acc2 = __builtin_amdgcn_mfma_f32_32x32x16_bf16(a, w2p[ks << 6], acc2, 0, 0, 0);
        }

        // ---- epilogue: out = k1*sig(scales)*(f+b2) + k2*y
        // per store instruction: 2 rows x 32 lanes x 4B = 128B/row (no RMW)
        {
            const int n = ncol + nl;
            const float c1  = k1 * sigmoid_f(scales[n]);
            const float b2v = b2[(e << 8) | n];
#pragma unroll
            for (int r = 0; r < 16; ++r) {
                const int row = (r & 3) + ((r >> 2) << 3) + (kh << 2);
                const int g = rows[row];
                if (g >= 0) {
                    float res = c1 * (acc2[r] + b2v);
                    if (needy) res += k2 * y[(long)g * DIM + n];
                    out[(long)g * DIM + n] = res;
                }
            }
        }
    }
}

extern "C" void kernel_launch(void* const* d_in, const int* in_sizes, int n_in,
                              void* d_out, int out_size, void* d_ws, size_t ws_size,
                              hipStream_t stream) {
    const float* t      = (const float*)d_in[0];
    const float* y      = (const float*)d_in[1];
    const float* W1     = (const float*)d_in[2];
    const float* b1     = (const float*)d_in[3];
    const float* W2     = (const float*)d_in[4];
    const float* b2     = (const float*)d_in[5];
    const float* scales = (const float*)d_in[6];
    const float* shifta = (const float*)d_in[7];
    const float* shiftb = (const float*)d_in[8];
    float* out = (float*)d_out;

    char* ws = (char*)d_ws;
    int* cursor = (int*)ws;                               // [8]
    int* idxb   = (int*)(ws + 256);                       // [8][32768]
    bf16x8* W1p = (bf16x8*)(ws + 256 + NEXP * BATCH * 4); // packed 1MB
    bf16x8* W2p = W1p + 65536;

    hipMemsetAsync(cursor, 0, 32, stream);
    prep_kernel<<<384, 256, 0, stream>>>(W1, W2, t, W1p, W2p, cursor, idxb);
    // max tiles = 8 + 32768/32 = 1032
    mlp_kernel<<<1032, 512, 0, stream>>>(y, scales, shifta, shiftb, b1, b2,
                                         W1p, W2p, cursor, idxb, out);
}